// Round 3
// baseline (345.285 us; speedup 1.0000x reference)
//
#include <hip/hip_runtime.h>
#include <hip/hip_bf16.h>
#include <hip/hip_fp16.h>
#include <math.h>

#define EMB 1024
#define SEQ 2048
#define BATCH 4

typedef _Float16 half8 __attribute__((ext_vector_type(8)));
typedef float floatx4 __attribute__((ext_vector_type(4)));

__device__ __forceinline__ void gload_lds16(const void* g, void* l) {
    __builtin_amdgcn_global_load_lds(
        (const __attribute__((address_space(1))) void*)g,
        (__attribute__((address_space(3))) void*)l, 16, 0, 0);
}

// C[M,N] = A[M,K] * Bt[N,K]^T  (both fp16 row-major, K contiguous), fp32 accum.
// EPI: 0 = fp16 out + bias; 1 = fp16 out written transposed per-batch (+bias)
//      2 = fp32 out, no bias; 3 = fp32 out + bias + relu; 4 = fp16 out, no bias
template <int EPI>
__global__ __launch_bounds__(256) void gemm_bt(
    const _Float16* __restrict__ A, const _Float16* __restrict__ B,
    void* __restrict__ Cv, const float* __restrict__ bias,
    int M, int N, int K, long sAb, long sBb, long sCb) {
    __shared__ _Float16 As[128 * 64];
    __shared__ _Float16 Bs[128 * 64];
    const int tid = threadIdx.x;
    const int lane = tid & 63;
    const int wave = tid >> 6;
    const long zb = blockIdx.z;
    A += zb * sAb;
    B += zb * sBb;
    const int bm = blockIdx.x * 128;
    const int bn = blockIdx.y * 128;
    floatx4 acc[4][4];
#pragma unroll
    for (int mi = 0; mi < 4; ++mi)
#pragma unroll
        for (int ni = 0; ni < 4; ++ni) acc[mi][ni] = (floatx4){0.f, 0.f, 0.f, 0.f};

    const int row_in = lane >> 3;       // 0..7
    const int col_in = (lane & 7) * 8;  // 0..56
    const int wm = (wave >> 1) * 64;
    const int wn = (wave & 1) * 64;
    const int fr = lane & 15;
    const int fk = (lane >> 4) * 8;

    for (int kt = 0; kt < K; kt += 64) {
#pragma unroll
        for (int c = 0; c < 4; ++c) {
            const int cc = wave * 4 + c;
            const _Float16* ga = A + (long)(bm + cc * 8 + row_in) * K + kt + col_in;
            gload_lds16(ga, &As[cc * 512]);
            const _Float16* gb = B + (long)(bn + cc * 8 + row_in) * K + kt + col_in;
            gload_lds16(gb, &Bs[cc * 512]);
        }
        __syncthreads();
#pragma unroll
        for (int kk = 0; kk < 64; kk += 32) {
            half8 af[4], bf[4];
#pragma unroll
            for (int mi = 0; mi < 4; ++mi)
                af[mi] = *(const half8*)&As[(wm + mi * 16 + fr) * 64 + kk + fk];
#pragma unroll
            for (int ni = 0; ni < 4; ++ni)
                bf[ni] = *(const half8*)&Bs[(wn + ni * 16 + fr) * 64 + kk + fk];
#pragma unroll
            for (int mi = 0; mi < 4; ++mi)
#pragma unroll
                for (int ni = 0; ni < 4; ++ni)
                    acc[mi][ni] = __builtin_amdgcn_mfma_f32_16x16x32_f16(
                        af[mi], bf[ni], acc[mi][ni], 0, 0, 0);
        }
        __syncthreads();
    }

    const int er = (lane >> 4) * 4;
    const int ec = lane & 15;
#pragma unroll
    for (int mi = 0; mi < 4; ++mi) {
#pragma unroll
        for (int ni = 0; ni < 4; ++ni) {
            const int col = bn + wn + ni * 16 + ec;
#pragma unroll
            for (int r = 0; r < 4; ++r) {
                const int row = bm + wm + mi * 16 + er + r;
                float v = acc[mi][ni][r];
                if (EPI == 0 || EPI == 1 || EPI == 3) v += bias[col];
                if (EPI == 3) v = fmaxf(v, 0.f);
                if (EPI == 0 || EPI == 4) {
                    ((_Float16*)Cv)[zb * sCb + (long)row * N + col] = (_Float16)v;
                } else if (EPI == 1) {
                    const long b = row >> 11;      // row / SEQ
                    const long i = row & (SEQ - 1);
                    ((_Float16*)Cv)[(b * EMB + col) * SEQ + i] = (_Float16)v;
                } else {
                    ((float*)Cv)[zb * sCb + (long)row * N + col] = v;
                }
            }
        }
    }
}

// row-softmax over SEQ fp32 elements -> fp16
__global__ __launch_bounds__(256) void softmax_rows(const float* __restrict__ P,
                                                    _Float16* __restrict__ Aout) {
    const long row = blockIdx.x;
    const float* p = P + row * (long)SEQ;
    const int tid = threadIdx.x;
    float4 x0 = ((const float4*)p)[2 * tid];
    float4 x1 = ((const float4*)p)[2 * tid + 1];
    float v[8] = {x0.x, x0.y, x0.z, x0.w, x1.x, x1.y, x1.z, x1.w};
    float m = v[0];
#pragma unroll
    for (int j = 1; j < 8; ++j) m = fmaxf(m, v[j]);
#pragma unroll
    for (int o = 32; o; o >>= 1) m = fmaxf(m, __shfl_xor(m, o));
    __shared__ float rbuf[4];
    __shared__ float sbuf[4];
    const int lane = tid & 63, wv = tid >> 6;
    if (!lane) rbuf[wv] = m;
    __syncthreads();
    m = fmaxf(fmaxf(rbuf[0], rbuf[1]), fmaxf(rbuf[2], rbuf[3]));
    float s = 0.f;
#pragma unroll
    for (int j = 0; j < 8; ++j) {
        v[j] = expf(v[j] - m);
        s += v[j];
    }
#pragma unroll
    for (int o = 32; o; o >>= 1) s += __shfl_xor(s, o);
    if (!lane) sbuf[wv] = s;
    __syncthreads();
    s = sbuf[0] + sbuf[1] + sbuf[2] + sbuf[3];
    const float inv = 1.f / s;
    half8 h;
#pragma unroll
    for (int j = 0; j < 8; ++j) h[j] = (_Float16)(v[j] * inv);
    *(half8*)(Aout + row * (long)SEQ + tid * 8) = h;
}

__global__ __launch_bounds__(256) void cast_x(const float* __restrict__ X,
                                              _Float16* __restrict__ Xh) {
    const long i = (long)(blockIdx.x * 256 + threadIdx.x) * 8;
    float4 a = ((const float4*)(X + i))[0];
    float4 b = ((const float4*)(X + i))[1];
    half8 h;
    h[0] = (_Float16)a.x; h[1] = (_Float16)a.y; h[2] = (_Float16)a.z; h[3] = (_Float16)a.w;
    h[4] = (_Float16)b.x; h[5] = (_Float16)b.y; h[6] = (_Float16)b.z; h[7] = (_Float16)b.w;
    *(half8*)(Xh + i) = h;
}

// Wt[n][k] = (fp16) W[k][n]
__global__ __launch_bounds__(256) void transpose_cast(const float* __restrict__ W,
                                                      _Float16* __restrict__ Wt) {
    __shared__ float tile[32][33];
    const int bx = blockIdx.x * 32;  // n
    const int by = blockIdx.y * 32;  // k
    const int tx = threadIdx.x, ty = threadIdx.y;
#pragma unroll
    for (int r = 0; r < 32; r += 8)
        tile[ty + r][tx] = W[(long)(by + ty + r) * EMB + bx + tx];
    __syncthreads();
#pragma unroll
    for (int r = 0; r < 32; r += 8)
        Wt[(long)(bx + ty + r) * EMB + by + tx] = (_Float16)tile[tx][ty + r];
}

extern "C" void kernel_launch(void* const* d_in, const int* in_sizes, int n_in,
                              void* d_out, int out_size, void* d_ws, size_t ws_size,
                              hipStream_t stream) {
    const float* x  = (const float*)d_in[0];
    const float* Wq = (const float*)d_in[1];
    const float* bq = (const float*)d_in[2];
    const float* Wk = (const float*)d_in[3];
    const float* bk = (const float*)d_in[4];
    const float* Wv = (const float*)d_in[5];
    const float* bv = (const float*)d_in[6];
    const float* Wm = (const float*)d_in[7];
    const float* bm = (const float*)d_in[8];
    float* out = (float*)d_out;

    char* ws = (char*)d_ws;
    const long MB = 1l << 20;
    _Float16* xh  = (_Float16*)(ws + 0 * MB);    // 16 MiB
    _Float16* wqt = (_Float16*)(ws + 16 * MB);   // 2 MiB
    _Float16* wkt = (_Float16*)(ws + 18 * MB);
    _Float16* wvt = (_Float16*)(ws + 20 * MB);
    _Float16* wmt = (_Float16*)(ws + 22 * MB);
    _Float16* q   = (_Float16*)(ws + 24 * MB);   // 16 MiB
    _Float16* k   = (_Float16*)(ws + 40 * MB);   // 16 MiB
    _Float16* vt  = (_Float16*)(ws + 56 * MB);   // 16 MiB  [B][EMB][SEQ]
    _Float16* t   = (_Float16*)(ws + 72 * MB);   // 16 MiB
    float*    P   = (float*)(ws + 88 * MB);      // 64 MiB  [B][SEQ][SEQ]
    _Float16* al  = (_Float16*)(ws + 152 * MB);  // 32 MiB

    const long MN = (long)BATCH * SEQ;  // 8192 rows total

    cast_x<<<4096, 256, 0, stream>>>(x, xh);
    transpose_cast<<<dim3(32, 32), dim3(32, 8), 0, stream>>>(Wq, wqt);
    transpose_cast<<<dim3(32, 32), dim3(32, 8), 0, stream>>>(Wk, wkt);
    transpose_cast<<<dim3(32, 32), dim3(32, 8), 0, stream>>>(Wv, wvt);
    transpose_cast<<<dim3(32, 32), dim3(32, 8), 0, stream>>>(Wm, wmt);

    // q = x@Wq + bq ; k = x@Wk + bk ; v = x@Wv + bv (written transposed per batch)
    gemm_bt<0><<<dim3(64, 8), 256, 0, stream>>>(xh, wqt, q, bq, (int)MN, EMB, EMB, 0, 0, 0);
    gemm_bt<0><<<dim3(64, 8), 256, 0, stream>>>(xh, wkt, k, bk, (int)MN, EMB, EMB, 0, 0, 0);
    gemm_bt<1><<<dim3(64, 8), 256, 0, stream>>>(xh, wvt, vt, bv, (int)MN, EMB, EMB, 0, 0, 0);

    // P[b][j][i] = k_j . q_i
    gemm_bt<2><<<dim3(16, 16, BATCH), 256, 0, stream>>>(
        k, q, P, nullptr, SEQ, SEQ, EMB,
        (long)SEQ * EMB, (long)SEQ * EMB, (long)SEQ * SEQ);

    // alpha = row-softmax(P)  (softmax over i)
    softmax_rows<<<BATCH * SEQ, 256, 0, stream>>>(P, al);

    // t[b][j][d] = sum_i alpha[j][i] * vt[d][i]
    gemm_bt<4><<<dim3(16, 8, BATCH), 256, 0, stream>>>(
        al, vt, t, nullptr, SEQ, EMB, SEQ,
        (long)SEQ * SEQ, (long)EMB * SEQ, (long)SEQ * EMB);

    // out = relu(t @ Wm + bm)
    gemm_bt<3><<<dim3(64, 8), 256, 0, stream>>>(t, wmt, out, bm, (int)MN, EMB, EMB, 0, 0, 0);
}